// Round 6
// baseline (272.404 us; speedup 1.0000x reference)
//
#include <hip/hip_runtime.h>
#include <hip/hip_bf16.h>

#define B_ 256
#define S_ 512
#define H_ 300
#define NL_ 7
#define NT_ 320   // block threads (5 waves); 300 active for H-dim work
#define NCHUNK_ 4
#define SPER_ (S_ / NCHUNK_)     // 128 tokens per gather block
#define NGATHER_ (B_ * NCHUNK_)  // 1024 blocks

#define Q_ (H_ / 4)   // 75 float4 per row

__device__ __forceinline__ void f4add(float4& a, const float4 b) {
  a.x += b.x; a.y += b.y; a.z += b.z; a.w += b.w;
}

// Fused: 1024 gather blocks; the last block of each batch row (atomic counter)
// continues into that row's MLP+logp; the last row triggers the fixed-order
// loss reduction. All reductions fixed-order -> bitwise deterministic.
__global__ __launch_bounds__(NT_) void dan_fused(
    const int* __restrict__ ids, const int* __restrict__ am,
    const int* __restrict__ labels, const int* __restrict__ drop,
    const float* __restrict__ emb,
    const float* __restrict__ W1, const float* __restrict__ b1,
    const float* __restrict__ W2, const float* __restrict__ b2,
    const float* __restrict__ W3, const float* __restrict__ b3,
    float* __restrict__ out, float* __restrict__ partial,
    float* __restrict__ perloss, unsigned* __restrict__ rowcnt,
    unsigned* __restrict__ donecnt) {
  const int gb = blockIdx.x;
  const int b = gb >> 2, c = gb & 3;
  const int t = threadIdx.x;

  __shared__ int sid[SPER_];
  __shared__ __align__(16) float sacc[4][H_];
  __shared__ __align__(16) float savg[H_];
  __shared__ __align__(16) float sh[H_];
  __shared__ float swred[NT_ / 64];
  __shared__ float snz;
  __shared__ float slog[NL_];
  __shared__ unsigned sold;

  // ---- phase 1: gather 128 tokens (4 subgroups x 75 float4 lanes) ----
  if (t < SPER_) {
    int off = b * S_ + c * SPER_ + t;
    sid[t] = ids[off] * am[off];
  }
  __syncthreads();

  if (t < H_) {
    const int grp = t / Q_;       // 0..3
    const int dq = t - grp * Q_;  // 0..74
    const float* ebase = emb + 4 * dq;
    float4 a0 = {0.f, 0.f, 0.f, 0.f}, a1 = {0.f, 0.f, 0.f, 0.f};
#pragma unroll 8
    for (int it = 0; it < SPER_ / 4; ++it) {  // 32 iterations
      int id = sid[4 * it + grp];
      const float4 v =
          *reinterpret_cast<const float4*>(ebase + (size_t)id * H_);
      if (it & 1) f4add(a1, v); else f4add(a0, v);
    }
    f4add(a0, a1);
    *reinterpret_cast<float4*>(&sacc[grp][4 * dq]) = a0;
  }
  __syncthreads();

  if (t < H_)
    partial[gb * H_ + t] =
        (sacc[0][t] + sacc[1][t]) + (sacc[2][t] + sacc[3][t]);

  // ---- publish partials, elect per-row finisher ----
  __threadfence();
  __syncthreads();
  if (t == 0) sold = atomicAdd(&rowcnt[b], 1u);
  __syncthreads();
  if (sold != NCHUNK_ - 1) return;  // not the last chunk of this row
  __threadfence();                  // acquire: see other chunks' partials

  // ---- phase 2 (finisher): drop-mask sum ----
  int nzp = 0;
  for (int s = t; s < S_; s += NT_) nzp += drop[b * S_ + s];
  for (int o = 32; o > 0; o >>= 1) nzp += __shfl_down(nzp, o, 64);
  if ((t & 63) == 0) swred[t >> 6] = (float)nzp;
  __syncthreads();
  if (t == 0) {
    float s = 0.f;
    for (int w = 0; w < NT_ / 64; ++w) s += swred[w];
    snz = s;
  }
  __syncthreads();

  // avg over the 4 partial chunks (fixed order)
  if (t < H_) {
    float s = 0.f;
#pragma unroll
    for (int cc = 0; cc < NCHUNK_; ++cc)
      s += partial[(b * NCHUNK_ + cc) * H_ + t];
    savg[t] = s / snz;
  }
  __syncthreads();

  // h1 = relu(W1 @ avg + b1)
  if (t < H_) {
    const float4* w = reinterpret_cast<const float4*>(W1 + (size_t)t * H_);
    const float4* x = reinterpret_cast<const float4*>(savg);
    float4 a = {0.f, 0.f, 0.f, 0.f};
#pragma unroll 5
    for (int j = 0; j < Q_; ++j) {
      float4 wv = w[j], xv = x[j];
      a.x = fmaf(wv.x, xv.x, a.x);
      a.y = fmaf(wv.y, xv.y, a.y);
      a.z = fmaf(wv.z, xv.z, a.z);
      a.w = fmaf(wv.w, xv.w, a.w);
    }
    sh[t] = fmaxf(b1[t] + (a.x + a.y) + (a.z + a.w), 0.f);
  }
  __syncthreads();

  // h2 = relu(W2 @ h1 + b2)  (into savg)
  if (t < H_) {
    const float4* w = reinterpret_cast<const float4*>(W2 + (size_t)t * H_);
    const float4* x = reinterpret_cast<const float4*>(sh);
    float4 a = {0.f, 0.f, 0.f, 0.f};
#pragma unroll 5
    for (int j = 0; j < Q_; ++j) {
      float4 wv = w[j], xv = x[j];
      a.x = fmaf(wv.x, xv.x, a.x);
      a.y = fmaf(wv.y, xv.y, a.y);
      a.z = fmaf(wv.z, xv.z, a.z);
      a.w = fmaf(wv.w, xv.w, a.w);
    }
    savg[t] = fmaxf(b2[t] + (a.x + a.y) + (a.z + a.w), 0.f);
  }
  __syncthreads();

  // logits = W3 @ h2 + b3
  if (t < NL_) {
    const float4* w = reinterpret_cast<const float4*>(W3 + (size_t)t * H_);
    const float4* x = reinterpret_cast<const float4*>(savg);
    float4 a = {0.f, 0.f, 0.f, 0.f};
#pragma unroll 5
    for (int j = 0; j < Q_; ++j) {
      float4 wv = w[j], xv = x[j];
      a.x = fmaf(wv.x, xv.x, a.x);
      a.y = fmaf(wv.y, xv.y, a.y);
      a.z = fmaf(wv.z, xv.z, a.z);
      a.w = fmaf(wv.w, xv.w, a.w);
    }
    float acc = b3[t] + (a.x + a.y) + (a.z + a.w);
    slog[t] = acc;
    out[1 + b * NL_ + t] = acc;
  }
  __syncthreads();

  if (t == 0) {
    float m = slog[0];
    for (int cc = 1; cc < NL_; ++cc) m = fmaxf(m, slog[cc]);
    float se = 0.f;
    for (int cc = 0; cc < NL_; ++cc) se += expf(slog[cc] - m);
    int lab = labels[b];
    perloss[b] = slog[lab] - m - logf(se);
  }

  // ---- phase 3: last row reduces the loss (fixed order) ----
  __syncthreads();
  if (t == 0) {
    __threadfence();
    sold = atomicAdd(donecnt, 1u);
  }
  __syncthreads();
  if (sold == B_ - 1) {
    __threadfence();
    if (t < 64) {
      float v = perloss[t] + perloss[t + 64] + perloss[t + 128] +
                perloss[t + 192];
      for (int o = 32; o > 0; o >>= 1) v += __shfl_xor(v, o, 64);
      if (t == 0) out[0] = -v * (1.0f / (float)B_);
    }
  }
}

extern "C" void kernel_launch(void* const* d_in, const int* in_sizes, int n_in,
                              void* d_out, int out_size, void* d_ws,
                              size_t ws_size, hipStream_t stream) {
  const int* ids = (const int*)d_in[0];
  const int* am = (const int*)d_in[1];
  const int* labels = (const int*)d_in[2];
  const int* drop = (const int*)d_in[3];
  const float* emb = (const float*)d_in[4];
  const float* W1 = (const float*)d_in[5];
  const float* b1 = (const float*)d_in[6];
  const float* W2 = (const float*)d_in[7];
  const float* b2 = (const float*)d_in[8];
  const float* W3 = (const float*)d_in[9];
  const float* b3 = (const float*)d_in[10];
  float* out = (float*)d_out;

  float* partial = (float*)d_ws;                     // [1024][300]
  float* perloss = partial + (size_t)NGATHER_ * H_;  // [256]
  unsigned* rowcnt = (unsigned*)(perloss + B_);      // [256]
  unsigned* donecnt = rowcnt + B_;                   // [1]

  hipMemsetAsync(rowcnt, 0, (B_ + 1) * sizeof(unsigned), stream);
  dan_fused<<<NGATHER_, NT_, 0, stream>>>(ids, am, labels, drop, emb, W1, b1,
                                          W2, b2, W3, b3, out, partial,
                                          perloss, rowcnt, donecnt);
}

// Round 7
// 46.828 us; speedup vs baseline: 5.8171x; 5.8171x over previous
//
#include <hip/hip_runtime.h>
#include <hip/hip_bf16.h>

#define B_ 256
#define S_ 512
#define H_ 300
#define NL_ 7
#define NT_ 320   // block threads (5 waves); 300 active for H-dim work
#define NCHUNK_ 4
#define SPER_ (S_ / NCHUNK_)     // 128 tokens per gather block
#define NGATHER_ (B_ * NCHUNK_)  // 1024

#define Q_ (H_ / 4)   // 75 float4 per row

__device__ __forceinline__ void f4add(float4& a, const float4 b) {
  a.x += b.x; a.y += b.y; a.z += b.z; a.w += b.w;
}

// ---------------- Kernel A: masked embedding gather (8-deep ILP) -----------
// grid NGATHER_, block NT_. 4 token-subgroups x 75 float4-lanes; each thread
// issues 8 independent row-loads per iteration (forces high VGPR + 8
// outstanding VMEM ops -> latency hiding for the random-row gather).
__global__ __launch_bounds__(NT_) void dan_gather(
    const int* __restrict__ ids, const int* __restrict__ am,
    const float* __restrict__ emb, float* __restrict__ partial) {
  const int gb = blockIdx.x;
  const int b = gb >> 2, c = gb & 3;
  const int t = threadIdx.x;
  __shared__ int sid[SPER_];
  __shared__ __align__(16) float sacc[4][H_];

  if (t < SPER_) {
    int off = b * S_ + c * SPER_ + t;
    sid[t] = ids[off] * am[off];
  }
  __syncthreads();

  if (t < H_) {
    const int grp = t / Q_;       // 0..3
    const int dq = t - grp * Q_;  // 0..74
    const float* ebase = emb + 4 * dq;
    float4 a0 = {0.f, 0.f, 0.f, 0.f}, a1 = {0.f, 0.f, 0.f, 0.f};
    float4 a2 = {0.f, 0.f, 0.f, 0.f}, a3 = {0.f, 0.f, 0.f, 0.f};
#pragma unroll
    for (int it = 0; it < SPER_ / 32; ++it) {  // 4 iters x 8 tokens
      const int s0 = 32 * it + grp;  // tokens {32it + 4u + grp}
      const float4 v0 =
          *reinterpret_cast<const float4*>(ebase + (size_t)sid[s0] * H_);
      const float4 v1 =
          *reinterpret_cast<const float4*>(ebase + (size_t)sid[s0 + 4] * H_);
      const float4 v2 =
          *reinterpret_cast<const float4*>(ebase + (size_t)sid[s0 + 8] * H_);
      const float4 v3 =
          *reinterpret_cast<const float4*>(ebase + (size_t)sid[s0 + 12] * H_);
      const float4 v4 =
          *reinterpret_cast<const float4*>(ebase + (size_t)sid[s0 + 16] * H_);
      const float4 v5 =
          *reinterpret_cast<const float4*>(ebase + (size_t)sid[s0 + 20] * H_);
      const float4 v6 =
          *reinterpret_cast<const float4*>(ebase + (size_t)sid[s0 + 24] * H_);
      const float4 v7 =
          *reinterpret_cast<const float4*>(ebase + (size_t)sid[s0 + 28] * H_);
      f4add(a0, v0); f4add(a1, v1); f4add(a2, v2); f4add(a3, v3);
      f4add(a0, v4); f4add(a1, v5); f4add(a2, v6); f4add(a3, v7);
    }
    f4add(a0, a1); f4add(a2, a3); f4add(a0, a2);
    *reinterpret_cast<float4*>(&sacc[grp][4 * dq]) = a0;
  }
  __syncthreads();

  if (t < H_)
    partial[gb * H_ + t] =
        (sacc[0][t] + sacc[1][t]) + (sacc[2][t] + sacc[3][t]);
}

// ---------------- Kernel B: partial-reduce + 3-layer MLP + logp ------------
__global__ __launch_bounds__(NT_) void dan_mlp(
    const float* __restrict__ partial, const int* __restrict__ drop,
    const int* __restrict__ labels,
    const float* __restrict__ W1, const float* __restrict__ b1,
    const float* __restrict__ W2, const float* __restrict__ b2,
    const float* __restrict__ W3, const float* __restrict__ b3,
    float* __restrict__ out, float* __restrict__ perloss) {
  const int b = blockIdx.x, t = threadIdx.x;
  __shared__ __align__(16) float savg[H_];
  __shared__ __align__(16) float sh[H_];
  __shared__ float swred[NT_ / 64];
  __shared__ float snz;
  __shared__ float slog[NL_];

  // nonzeros[b] = sum_s drop_mask[b,s]
  int nzp = 0;
  for (int s = t; s < S_; s += NT_) nzp += drop[b * S_ + s];
  for (int o = 32; o > 0; o >>= 1) nzp += __shfl_down(nzp, o, 64);
  if ((t & 63) == 0) swred[t >> 6] = (float)nzp;
  __syncthreads();
  if (t == 0) {
    float s = 0.f;
    for (int w = 0; w < NT_ / 64; ++w) s += swred[w];
    snz = s;
  }
  __syncthreads();

  if (t < H_) {
    float s = 0.f;
#pragma unroll
    for (int c = 0; c < NCHUNK_; ++c) s += partial[(b * NCHUNK_ + c) * H_ + t];
    savg[t] = s / snz;
  }
  __syncthreads();

  // h1 = relu(W1 @ avg + b1)
  if (t < H_) {
    const float4* w = reinterpret_cast<const float4*>(W1 + (size_t)t * H_);
    const float4* x = reinterpret_cast<const float4*>(savg);
    float4 a = {0.f, 0.f, 0.f, 0.f};
#pragma unroll 5
    for (int j = 0; j < Q_; ++j) {
      float4 wv = w[j], xv = x[j];
      a.x = fmaf(wv.x, xv.x, a.x);
      a.y = fmaf(wv.y, xv.y, a.y);
      a.z = fmaf(wv.z, xv.z, a.z);
      a.w = fmaf(wv.w, xv.w, a.w);
    }
    sh[t] = fmaxf(b1[t] + (a.x + a.y) + (a.z + a.w), 0.f);
  }
  __syncthreads();

  // h2 = relu(W2 @ h1 + b2)  (into savg; h1-phase reads done)
  if (t < H_) {
    const float4* w = reinterpret_cast<const float4*>(W2 + (size_t)t * H_);
    const float4* x = reinterpret_cast<const float4*>(sh);
    float4 a = {0.f, 0.f, 0.f, 0.f};
#pragma unroll 5
    for (int j = 0; j < Q_; ++j) {
      float4 wv = w[j], xv = x[j];
      a.x = fmaf(wv.x, xv.x, a.x);
      a.y = fmaf(wv.y, xv.y, a.y);
      a.z = fmaf(wv.z, xv.z, a.z);
      a.w = fmaf(wv.w, xv.w, a.w);
    }
    savg[t] = fmaxf(b2[t] + (a.x + a.y) + (a.z + a.w), 0.f);
  }
  __syncthreads();

  // logits = W3 @ h2 + b3
  if (t < NL_) {
    const float4* w = reinterpret_cast<const float4*>(W3 + (size_t)t * H_);
    const float4* x = reinterpret_cast<const float4*>(savg);
    float4 a = {0.f, 0.f, 0.f, 0.f};
#pragma unroll 5
    for (int j = 0; j < Q_; ++j) {
      float4 wv = w[j], xv = x[j];
      a.x = fmaf(wv.x, xv.x, a.x);
      a.y = fmaf(wv.y, xv.y, a.y);
      a.z = fmaf(wv.z, xv.z, a.z);
      a.w = fmaf(wv.w, xv.w, a.w);
    }
    float acc = b3[t] + (a.x + a.y) + (a.z + a.w);
    slog[t] = acc;
    out[1 + b * NL_ + t] = acc;
  }
  __syncthreads();

  if (t == 0) {
    float m = slog[0];
    for (int c = 1; c < NL_; ++c) m = fmaxf(m, slog[c]);
    float se = 0.f;
    for (int c = 0; c < NL_; ++c) se += expf(slog[c] - m);
    int lab = labels[b];
    perloss[b] = slog[lab] - m - logf(se);
  }
}

// ---------------- Kernel C: deterministic loss reduction -------------------
__global__ void dan_loss(const float* __restrict__ perloss,
                         float* __restrict__ out) {
  const int t = threadIdx.x;  // 256 threads
  float v = perloss[t];
  for (int o = 32; o > 0; o >>= 1) v += __shfl_down(v, o, 64);
  __shared__ float r[4];
  if ((t & 63) == 0) r[t >> 6] = v;
  __syncthreads();
  if (t == 0) out[0] = -(r[0] + r[1] + r[2] + r[3]) * (1.0f / B_);
}

extern "C" void kernel_launch(void* const* d_in, const int* in_sizes, int n_in,
                              void* d_out, int out_size, void* d_ws,
                              size_t ws_size, hipStream_t stream) {
  const int* ids = (const int*)d_in[0];
  const int* am = (const int*)d_in[1];
  const int* labels = (const int*)d_in[2];
  const int* drop = (const int*)d_in[3];
  const float* emb = (const float*)d_in[4];
  const float* W1 = (const float*)d_in[5];
  const float* b1 = (const float*)d_in[6];
  const float* W2 = (const float*)d_in[7];
  const float* b2 = (const float*)d_in[8];
  const float* W3 = (const float*)d_in[9];
  const float* b3 = (const float*)d_in[10];
  float* out = (float*)d_out;

  float* partial = (float*)d_ws;                     // [1024][300]
  float* perloss = partial + (size_t)NGATHER_ * H_;  // [256]

  dan_gather<<<NGATHER_, NT_, 0, stream>>>(ids, am, emb, partial);
  dan_mlp<<<B_, NT_, 0, stream>>>(partial, drop, labels, W1, b1, W2, b2, W3,
                                  b3, out, perloss);
  dan_loss<<<1, B_, 0, stream>>>(perloss, out);
}